// Round 8
// baseline (76.608 us; speedup 1.0000x reference)
//
#include <hip/hip_runtime.h>
#include <hip/hip_bf16.h>
#include <math.h>

typedef __bf16 bf16;
typedef __bf16 bf16x8 __attribute__((ext_vector_type(8)));
typedef float  f32x4  __attribute__((ext_vector_type(4)));
typedef float  f32x16 __attribute__((ext_vector_type(16)));
typedef uint32_t u32x4 __attribute__((ext_vector_type(4)));

#define MFMA16(a, b, c) __builtin_amdgcn_mfma_f32_16x16x32_bf16((a), (b), (c), 0, 0, 0)
#define MFMA32(a, b, c) __builtin_amdgcn_mfma_f32_32x32x16_bf16((a), (b), (c), 0, 0, 0)

typedef const uint32_t __attribute__((address_space(1)))* gq_t;
typedef uint32_t __attribute__((address_space(3)))* lq_t;

constexpr int B_ = 8, C_ = 80, T_ = 2048, D_ = 256;
constexpr int NS = 8;                        // j-splits (4 blocks/CU)
constexpr float SCALE_INV = 1.0f / 16.0f;    // 1/sqrt(256)
// exp(x/16) = exp2(x * log2(e)/16): fold the softmax scale into v_exp's base-2 arg
constexpr float LOG2E_16 = 0.090169989f;     // log2(e)/16

static __device__ inline uint32_t pkbf(float lo, float hi) {
  bf16 l = (bf16)lo, h = (bf16)hi;
  uint16_t lb = __builtin_bit_cast(uint16_t, l), hb = __builtin_bit_cast(uint16_t, h);
  return (uint32_t)lb | ((uint32_t)hb << 16);
}

// ---------------------------------------------------------------------------
// Kernel 1: projection (unchanged). K/Q = xt@W^T + b (bf16), x -> bf16 copy.
// ---------------------------------------------------------------------------
__global__ __launch_bounds__(256) void proj_kernel(
    const float* __restrict__ x,   // [B][C][T]
    const float* __restrict__ Wk,  // [D][C]
    const float* __restrict__ bk,  // [D]
    const float* __restrict__ Wq,  // [D][C]
    const float* __restrict__ bq,  // [D]
    bf16* __restrict__ Kb,         // [B][T][D]
    bf16* __restrict__ Qb,         // [B][T][D]
    bf16* __restrict__ xbf)        // [B][C][T]
{
  const int t0   = blockIdx.x * 32;
  const int b    = blockIdx.y;
  const int tid  = threadIdx.x;
  const int w    = tid >> 6;
  const int lane = tid & 63;
  const int h    = lane >> 4;
  const int lr   = lane & 15;

  const float* xb = x + (size_t)b * C_ * T_;

  {
    bf16* ob = xbf + (size_t)b * C_ * T_;
    #pragma unroll
    for (int q = 0; q < 10; ++q) {
      int idx = q * 256 + tid;
      int c = idx >> 5, tt = idx & 31;
      ob[c * T_ + t0 + tt] = (bf16)xb[c * T_ + t0 + tt];
    }
  }

  bf16x8 afrag[2][3];
  #pragma unroll
  for (int ib = 0; ib < 2; ++ib) {
    int t = t0 + ib * 16 + lr;
    #pragma unroll
    for (int ks = 0; ks < 3; ++ks) {
      bf16x8 v;
      #pragma unroll
      for (int e = 0; e < 8; ++e) {
        int c = ks * 32 + h * 8 + e;
        float val;
        if (c < 80)       val = xb[c * T_ + t];
        else if (c == 80) val = 1.0f;
        else              val = 0.0f;
        v[e] = (bf16)val;
      }
      afrag[ib][ks] = v;
    }
  }

  const int nb0 = w * 4;
  #pragma unroll
  for (int mat = 0; mat < 2; ++mat) {
    const float* W    = mat ? Wq : Wk;
    const float* bias = mat ? bq : bk;
    bf16* outp        = mat ? Qb : Kb;

    f32x4 acc[2][4];
    #pragma unroll
    for (int ib = 0; ib < 2; ++ib)
      #pragma unroll
      for (int nb = 0; nb < 4; ++nb)
        acc[ib][nb] = f32x4{0.f, 0.f, 0.f, 0.f};

    #pragma unroll
    for (int nb = 0; nb < 4; ++nb) {
      int d = (nb0 + nb) * 16 + lr;
      #pragma unroll
      for (int ks = 0; ks < 3; ++ks) {
        bf16x8 bv;
        #pragma unroll
        for (int e = 0; e < 8; ++e) {
          int c = ks * 32 + h * 8 + e;
          float val;
          if (c < 80)       val = W[d * C_ + c];
          else if (c == 80) val = bias[d];
          else              val = 0.0f;
          bv[e] = (bf16)val;
        }
        #pragma unroll
        for (int ib = 0; ib < 2; ++ib)
          acc[ib][nb] = MFMA16(afrag[ib][ks], bv, acc[ib][nb]);
      }
    }

    #pragma unroll
    for (int ib = 0; ib < 2; ++ib)
      #pragma unroll
      for (int nb = 0; nb < 4; ++nb) {
        int d = (nb0 + nb) * 16 + lr;
        #pragma unroll
        for (int r = 0; r < 4; ++r) {
          int t = t0 + ib * 16 + h * 4 + r;
          outp[(size_t)(b * T_ + t) * D_ + d] = (bf16)acc[ib][nb][r];
        }
      }
  }
}

// ---------------------------------------------------------------------------
// Kernel 2: flash attention, swapped-QK 32x32 structure (unchanged core),
// NS=8 j-splits -> 1024 blocks = 4/CU, exp2-folded softmax.
// ---------------------------------------------------------------------------
__global__ __launch_bounds__(256, 2) void attn_kernel(
    const bf16* __restrict__ Kb,   // [B][T][D]
    const bf16* __restrict__ Qb,   // [B][T][D]
    const bf16* __restrict__ xbf,  // [B][C][T]
    float* __restrict__ Opart,     // [NS][B][C][T]
    float* __restrict__ mpart,     // [NS][B][T]
    float* __restrict__ lpart)     // [NS][B][T]
{
  constexpr int BN = 32, NT = T_ / BN;   // 64 j-tiles total
  constexpr int JT_PER = NT / NS;        // 8 per split
  __shared__ bf16 qlds[2][BN * D_];      // 2 x 16 KB

  const int flat = blockIdx.x;
  const int b    = flat & 7;             // batch -> XCD
  const int rem  = flat >> 3;
  const int it   = rem & 15;             // 16 i-tiles of 128
  const int s    = rem >> 4;             // split 0..7
  const int i0   = it * 128;

  const int tid  = threadIdx.x;
  const int w    = tid >> 6;
  const int lane = tid & 63;
  const int il   = lane & 31;
  const int hi   = lane >> 5;
  const int iw   = i0 + w * 32;          // this wave's 32 i-rows

  const bf16* Kbase = Kb  + (size_t)b * T_ * D_;
  const bf16* Qbase = Qb  + (size_t)b * T_ * D_;
  const bf16* Vbase = xbf + (size_t)b * C_ * T_;

  // K B-frags (resident): kf[ks] = K[iw+il][hi*8 + ks*16 .. +7]
  bf16x8 kf[16];
  {
    const bf16* kp = Kbase + (size_t)(iw + il) * D_ + hi * 8;
    #pragma unroll
    for (int ks = 0; ks < 16; ++ks)
      kf[ks] = *reinterpret_cast<const bf16x8*>(kp + ks * 16);
  }

  f32x16 oacc[3];
  #pragma unroll
  for (int cb = 0; cb < 3; ++cb)
    #pragma unroll
    for (int r = 0; r < 16; ++r) oacc[cb][r] = 0.f;
  float m_run = -INFINITY, l_run = 0.f;

  // Q tile stage: LDS slot (j, c) holds Q[j][c ^ j] (16B chunks); linear LDS
  // dest, swizzle folded into the global source address.
  auto stage = [&](int jt, int buf) {
    #pragma unroll
    for (int q = 0; q < 4; ++q) {
      int f = tid + 256 * q;             // 16B-chunk id, 0..1023
      int j = f >> 5, c = f & 31;
      const bf16* src = Qbase + (size_t)(jt * BN + j) * D_ + ((c ^ j) << 3);
      __builtin_amdgcn_global_load_lds((gq_t)src,
          (lq_t)&qlds[buf][(q * 256 + w * 64) * 8], 16, 0, 0);
    }
  };

  const int jt0 = s * JT_PER, jtend = jt0 + JT_PER;

  stage(jt0, 0);
  asm volatile("s_waitcnt vmcnt(0)" ::: "memory");
  __syncthreads();

  int cur = 0;
  for (int jt = jt0; jt < jtend; ++jt, cur ^= 1) {
    if (jt + 1 < jtend) stage(jt + 1, cur ^ 1);   // prefetch -> other buffer

    // V^T A-frags from L2: vf[cb][kj] = xbf[cb*32+il][jt*32 + hi*8 + kj*16]
    bf16x8 vf[3][2];
    #pragma unroll
    for (int cb = 0; cb < 3; ++cb)
      #pragma unroll
      for (int kj = 0; kj < 2; ++kj)
        vf[cb][kj] = *reinterpret_cast<const bf16x8*>(
            Vbase + (size_t)(cb * 32 + il) * T_ + jt * BN + hi * 8 + kj * 16);

    // --- S^T = Q K^T: lane holds a 16-j slice of row i = iw + il ---
    f32x16 sacc;
    #pragma unroll
    for (int r = 0; r < 16; ++r) sacc[r] = 0.f;
    __builtin_amdgcn_s_setprio(1);
    #pragma unroll
    for (int ks = 0; ks < 16; ++ks) {
      bf16x8 qa = *reinterpret_cast<const bf16x8*>(
          &qlds[cur][il * 256 + (((hi + 2 * ks) ^ il) << 3)]);
      sacc = MFMA32(qa, kf[ks], sacc);
    }
    __builtin_amdgcn_s_setprio(0);

    // --- in-register online softmax (exp2-folded) ---
    float p16[16];
    #pragma unroll
    for (int r = 0; r < 16; ++r) p16[r] = sacc[r];
    float mx = p16[0];
    #pragma unroll
    for (int r = 1; r < 16; ++r) mx = fmaxf(mx, p16[r]);
    mx = fmaxf(mx, __shfl_xor(mx, 32));

    // defer-max (T13): raw threshold 48 = 3 score units (P <= e^3)
    if (!__all(mx <= m_run + 48.f)) {
      float mnew  = fmaxf(m_run, mx);
      float alpha = exp2f((m_run - mnew) * LOG2E_16);
      m_run = mnew;
      l_run *= alpha;
      #pragma unroll
      for (int cb = 0; cb < 3; ++cb)
        #pragma unroll
        for (int r = 0; r < 16; ++r) oacc[cb][r] *= alpha;
    }
    float rs = 0.f;
    #pragma unroll
    for (int r = 0; r < 16; ++r) {
      p16[r] = exp2f((p16[r] - m_run) * LOG2E_16);
      rs += p16[r];
    }
    rs += __shfl_xor(rs, 32);
    l_run += rs;

    // --- P -> bf16 B-frags in-register (pack + cross-half exchange) ---
    uint32_t a0 = pkbf(p16[0],  p16[1]),  a1 = pkbf(p16[2],  p16[3]);
    uint32_t c0 = pkbf(p16[4],  p16[5]),  c1 = pkbf(p16[6],  p16[7]);
    uint32_t a2 = pkbf(p16[8],  p16[9]),  a3 = pkbf(p16[10], p16[11]);
    uint32_t c2 = pkbf(p16[12], p16[13]), c3 = pkbf(p16[14], p16[15]);
    uint32_t a0s = __shfl_xor(a0, 32), a1s = __shfl_xor(a1, 32);
    uint32_t c0s = __shfl_xor(c0, 32), c1s = __shfl_xor(c1, 32);
    uint32_t a2s = __shfl_xor(a2, 32), a3s = __shfl_xor(a3, 32);
    uint32_t c2s = __shfl_xor(c2, 32), c3s = __shfl_xor(c3, 32);
    const bool h = (hi != 0);
    u32x4 pb0 = { h ? c0s : a0, h ? c1s : a1, h ? c0 : a0s, h ? c1 : a1s };
    u32x4 pb1 = { h ? c2s : a2, h ? c3s : a3, h ? c2 : a2s, h ? c3 : a3s };
    bf16x8 pbf0 = __builtin_bit_cast(bf16x8, pb0);
    bf16x8 pbf1 = __builtin_bit_cast(bf16x8, pb1);

    // --- PV: oacc[cb] += V^T[cb] . P ---
    __builtin_amdgcn_s_setprio(1);
    #pragma unroll
    for (int cb = 0; cb < 3; ++cb) {
      oacc[cb] = MFMA32(vf[cb][0], pbf0, oacc[cb]);
      oacc[cb] = MFMA32(vf[cb][1], pbf1, oacc[cb]);
    }
    __builtin_amdgcn_s_setprio(0);

    asm volatile("s_waitcnt vmcnt(0)" ::: "memory");  // next-tile stage done
    __syncthreads();
  }

  // --- epilogue: unnormalized partials ---
  float* ob = Opart + (size_t)(s * B_ + b) * C_ * T_;
  #pragma unroll
  for (int cb = 0; cb < 3; ++cb)
    #pragma unroll
    for (int r = 0; r < 16; ++r) {
      if (cb < 2 || r < 8) {
        int c = cb * 32 + (r & 3) + 8 * (r >> 2) + 4 * hi;
        ob[(size_t)c * T_ + iw + il] = oacc[cb][r];
      }
    }
  if (lane < 32) {
    mpart[(size_t)(s * B_ + b) * T_ + iw + il] = m_run;
    lpart[(size_t)(s * B_ + b) * T_ + iw + il] = l_run;
  }
}

// ---------------------------------------------------------------------------
// Kernel 3: merge splits (exp2-folded to match raw-domain m).
// ---------------------------------------------------------------------------
__global__ __launch_bounds__(256) void merge_kernel(
    const float* __restrict__ Opart,  // [NS][B][C][T]
    const float* __restrict__ mpart,  // [NS][B][T]
    const float* __restrict__ lpart,  // [NS][B][T]
    float* __restrict__ out)          // [B][C][T]
{
  const int b    = blockIdx.y;
  const int tid  = threadIdx.x;
  const int w    = tid >> 6;
  const int lane = tid & 63;
  const int t    = blockIdx.x * 64 + lane;

  float m[NS];
  float mmax = -INFINITY;
  #pragma unroll
  for (int s2 = 0; s2 < NS; ++s2) {
    m[s2] = mpart[(size_t)(s2 * B_ + b) * T_ + t];
    mmax = fmaxf(mmax, m[s2]);
  }
  float e[NS];
  float lsum = 0.f;
  #pragma unroll
  for (int s2 = 0; s2 < NS; ++s2) {
    e[s2] = exp2f((m[s2] - mmax) * LOG2E_16);
    lsum += e[s2] * lpart[(size_t)(s2 * B_ + b) * T_ + t];
  }
  const float inv = 1.0f / lsum;

  const int c0 = w * 20;
  for (int c = c0; c < c0 + 20; ++c) {
    float acc = 0.f;
    #pragma unroll
    for (int s2 = 0; s2 < NS; ++s2)
      acc += Opart[((size_t)(s2 * B_ + b) * C_ + c) * T_ + t] * e[s2];
    out[((size_t)b * C_ + c) * T_ + t] = acc * inv;
  }
}

// ---------------------------------------------------------------------------
extern "C" void kernel_launch(void* const* d_in, const int* in_sizes, int n_in,
                              void* d_out, int out_size, void* d_ws, size_t ws_size,
                              hipStream_t stream) {
  (void)in_sizes; (void)n_in; (void)out_size; (void)ws_size;
  const float* x  = (const float*)d_in[0];
  const float* Wk = (const float*)d_in[1];
  const float* bk = (const float*)d_in[2];
  const float* Wq = (const float*)d_in[3];
  const float* bq = (const float*)d_in[4];
  float* out = (float*)d_out;

  char* ws = (char*)d_ws;
  const size_t MB = 1024 * 1024;
  bf16*  Kb    = (bf16*)(ws);                 // 8 MB
  bf16*  Qb    = (bf16*)(ws + 8 * MB);        // 8 MB
  bf16*  xbf   = (bf16*)(ws + 16 * MB);       // 2.625 MB
  float* Opart = (float*)(ws + 19 * MB);      // NS*8*80*2048*4 = 41.94 MB
  float* mpart = (float*)(ws + 61 * MB);      // 512 KB
  float* lpart = (float*)(ws + 62 * MB);      // 512 KB

  dim3 blk(256);
  dim3 g1(T_ / 32, B_);
  proj_kernel<<<g1, blk, 0, stream>>>(x, Wk, bk, Wq, bq, Kb, Qb, xbf);
  attn_kernel<<<dim3(16 * NS * B_), blk, 0, stream>>>(Kb, Qb, xbf, Opart, mpart, lpart);
  dim3 g3(T_ / 64, B_);
  merge_kernel<<<g3, blk, 0, stream>>>(Opart, mpart, lpart, out);
}